// Round 15
// baseline (219.623 us; speedup 1.0000x reference)
//
#include <hip/hip_runtime.h>
#include <hip/hip_bf16.h>
#include <cfloat>
#include <math.h>

typedef __bf16 bf16;
typedef __bf16 bf16x4 __attribute__((ext_vector_type(4)));
typedef __bf16 bf16x8 __attribute__((ext_vector_type(8)));
typedef float  floatx4 __attribute__((ext_vector_type(4)));
typedef float  floatx2 __attribute__((ext_vector_type(2)));

#define SEQ 2048
#define DM  1024
#define NP  2048
#define MARGIN 0.5f
#define LBUF 1024

__device__ __forceinline__ unsigned enc_f(float f) {
  unsigned b = __float_as_uint(f);
  return ((int)b >= 0) ? (b | 0x80000000u) : ~b;
}
__device__ __forceinline__ float dec_f(unsigned u) {
  return (u & 0x80000000u) ? __uint_as_float(u & 0x7fffffffu) : __uint_as_float(~u);
}

// ===== fused prep: mask detect/compaction + inits + X split + W splits ======
// blocks [0,33): mask_prep; [33,2081): split_x; [2081,8225): split_w.
__global__ __launch_bounds__(256) void prep(
    const void* __restrict__ mraw, const float* __restrict__ X,
    const float* __restrict__ Wq, const float* __restrict__ Wk,
    const float* __restrict__ Wv,
    int* __restrict__ maskw, int* __restrict__ midx, int* __restrict__ mc,
    float* __restrict__ sums,
    unsigned long long* __restrict__ keys, unsigned* __restrict__ gmin,
    bf16* __restrict__ Xh, bf16* __restrict__ Xm,
    bf16* __restrict__ Tqh, bf16* __restrict__ Tqm,
    bf16* __restrict__ Tkh, bf16* __restrict__ Tkm,
    bf16* __restrict__ Tvh) {
  int b = blockIdx.x, t = threadIdx.x;
  if (b < 33) {
    if (b > 0) {
      int bb = b - 1;                 // 0..31
      for (int j = 0; j < 4; j++) {
        int i = bb * 1024 + j * 256 + t;
        keys[i] = ~0ULL;
        gmin[i] = 0xFFFFFFFFu;
      }
      if (bb == 0) for (int i = t; i < 2048; i += 256) sums[i] = 0.f;
      return;
    }
    __shared__ int flags;
    __shared__ int lmask[2048];
    if (t == 0) flags = 0;
    __syncthreads();
    const unsigned short* u16 = (const unsigned short*)mraw;
    const unsigned* u32 = (const unsigned*)mraw;
    int f = 0;
    for (int i = t; i < 1024; i += 256) {
      unsigned short v = u16[i];
      if (v != 0 && v != 0x3F80u) f |= 1;
      if ((i & 1) == 0 && v == 0x3F80u) f |= 2;
    }
    for (int i = t; i < 512; i += 256)
      if (u32[i] > 1u) f |= 4;
    if (f) atomicOr(&flags, f);
    __syncthreads();
    int fl = flags;
    int mode;
    if (!(fl & 1)) mode = (fl & 2) ? 2 : 3;
    else           mode = (fl & 4) ? 1 : 0;
    for (int s = t; s < SEQ; s += 256) {
      int m;
      if (mode == 0)      m = (((const int*)mraw)[s] != 0);
      else if (mode == 1) m = (((const unsigned char*)mraw)[s] != 0);
      else if (mode == 2) m = (u16[s] != 0);
      else                m = (((const float*)mraw)[s] != 0.0f);
      maskw[s] = m; lmask[s] = m;
    }
    __syncthreads();
    if (t < 64) {
      int base = 0;
      for (int c = 0; c < 32; c++) {
        int s = c * 64 + t;
        bool m = lmask[s] != 0;
        unsigned long long bal = __ballot(m);
        if (m) midx[base + __popcll(bal & ((1ULL << t) - 1ULL))] = s;
        base += __popcll(bal);
      }
      if (t == 0) *mc = base;
    }
    return;
  }
  if (b < 2081) {
    // ---- split_x: X -> 2-way bf16, row-major ----
    int i = (b - 33) * 256 + t;
    floatx4 v = *(const floatx4*)(X + (size_t)i * 4);
    bf16x4 hv, mv;
    #pragma unroll
    for (int j = 0; j < 4; j++) {
      float x = v[j];
      bf16 h = (bf16)x; float r1 = x - (float)h;
      hv[j] = h; mv[j] = (bf16)r1;
    }
    *(bf16x4*)(Xh + (size_t)i * 4) = hv;
    *(bf16x4*)(Xm + (size_t)i * 4) = mv;
    return;
  }
  // ---- split_w: transposed bf16 splits; z=0 Wq(2), z=1 Wk(2), z=2 Wv(h) ----
  int bb = b - 2081;
  int z = bb >> 11, rem = bb & 2047;
  int n0 = (rem & 63) * 32, k0 = (rem >> 6) * 32;
  const float* W = (z == 0) ? Wq : (z == 1) ? Wk : Wv;
  bf16* Th = (z == 0) ? Tqh : (z == 1) ? Tkh : Tvh;
  bf16* Tm = (z == 0) ? Tqm : Tkm;
  __shared__ float tile[32][33];
  int r = t >> 3, c4 = (t & 7) * 4;
  floatx4 v = *(const floatx4*)(W + (size_t)(k0 + r) * NP + n0 + c4);
  tile[r][c4 + 0] = v[0]; tile[r][c4 + 1] = v[1];
  tile[r][c4 + 2] = v[2]; tile[r][c4 + 3] = v[3];
  __syncthreads();
  bf16x4 hv, mv;
  #pragma unroll
  for (int j = 0; j < 4; j++) {
    float x = tile[c4 + j][r];
    bf16 h = (bf16)x; float r1 = x - (float)h;
    hv[j] = h; mv[j] = (bf16)r1;
  }
  size_t base = (size_t)(n0 + r) * DM + k0 + c4;
  *(bf16x4*)(Th + base) = hv;
  if (z < 2)
    *(bf16x4*)(Tm + base) = mv;
}

// ===== fused projections: blocks [0,1024) = Q/K, [1024,1536) = V + colsum ===
// A-tiles are NOT staged in LDS: each lane's A-fragment row is fixed
// (wm+i*16+l15), so A loads go direct global->register (L2-hot; X rows are
// shared by 16 head-blocks). LDS holds only B (20992B inc. colsum) -> 7
// blocks/CU, so all 1536 blocks co-reside (was 5/CU with a 256-block tail).
// B row stride [40]=80B stays a multiple of 16B (ds_*_b128 alignment).
__global__ __launch_bounds__(256) void proj_fused(
    const bf16* __restrict__ Xh, const bf16* __restrict__ Xm,
    const bf16* __restrict__ Qh_, const bf16* __restrict__ Qm_,
    const bf16* __restrict__ Kh_, const bf16* __restrict__ Km_,
    const bf16* __restrict__ Wvh,
    const float* __restrict__ bq, const float* __restrict__ bk,
    const float* __restrict__ bv,
    const int* __restrict__ midx, const int* __restrict__ mc,
    float* __restrict__ qf, float* __restrict__ kf,
    bf16* __restrict__ qbf, bf16* __restrict__ kbf,
    float* __restrict__ vf, float* __restrict__ sums) {
  __shared__ alignas(16) char smem[20992];
  int lin = blockIdx.x;
  int t = threadIdx.x, w = t >> 6, lane = t & 63, l15 = lane & 15, qd = lane >> 4;
  int wm = (w & 1) * 32, wn = (w >> 1) * 64;
  int bnr = t >> 1, bkb = (t & 1) * 16;
  if (lin < 1024) {
    int mcv = *mc;
    int z    = lin & 1;
    int head = (lin >> 1) & 15;
    int ms   = (lin >> 5) * 64;
    if (mcv == 0 || ms >= mcv) return;
    const bf16* WTh = z ? Kh_ : Qh_;
    const bf16* WTm = z ? Km_ : Qm_;
    const float* bia = z ? bk : bq;
    float* outf = z ? kf : qf;
    bf16*  outb = z ? kbf : qbf;
    int ns = head * 128;
    bf16 (*Bh)[40] = (bf16(*)[40])(smem);
    bf16 (*Bm)[40] = (bf16(*)[40])(smem + 10240);
    // direct A-fragment pointers (per-lane-fixed rows, clamped like staging)
    int fr0 = ms + wm + l15;
    int fr1 = ms + wm + 16 + l15;
    size_t fa0 = (size_t)midx[fr0 < mcv ? fr0 : (mcv - 1)] * DM + qd * 8;
    size_t fa1 = (size_t)midx[fr1 < mcv ? fr1 : (mcv - 1)] * DM + qd * 8;
    const bf16* xh0 = Xh + fa0;  const bf16* xh1 = Xh + fa1;
    const bf16* xm0 = Xm + fa0;  const bf16* xm1 = Xm + fa1;
    const bf16* bhp = WTh + (size_t)(ns + bnr) * DM + bkb;
    const bf16* bmp = WTm + (size_t)(ns + bnr) * DM + bkb;

    floatx4 acc[2][4];
    for (int i = 0; i < 2; i++)
      for (int j = 0; j < 4; j++) acc[i][j] = (floatx4){0.f, 0.f, 0.f, 0.f};

    bf16x8 pb[4], pah[2], pam[2];
    pb[0] = *(const bf16x8*)(bhp);     pb[1] = *(const bf16x8*)(bhp + 8);
    pb[2] = *(const bf16x8*)(bmp);     pb[3] = *(const bf16x8*)(bmp + 8);
    pah[0] = *(const bf16x8*)(xh0);    pah[1] = *(const bf16x8*)(xh1);
    pam[0] = *(const bf16x8*)(xm0);    pam[1] = *(const bf16x8*)(xm1);

    for (int kt = 0; kt < DM; kt += 32) {
      __syncthreads();
      *(bf16x8*)&Bh[bnr][bkb]     = pb[0];
      *(bf16x8*)&Bh[bnr][bkb + 8] = pb[1];
      *(bf16x8*)&Bm[bnr][bkb]     = pb[2];
      *(bf16x8*)&Bm[bnr][bkb + 8] = pb[3];
      __syncthreads();
      bf16x8 fah[2], fam[2];
      fah[0] = pah[0]; fah[1] = pah[1];
      fam[0] = pam[0]; fam[1] = pam[1];
      if (kt + 32 < DM) {
        int k2 = kt + 32;
        pb[0] = *(const bf16x8*)(bhp + k2);     pb[1] = *(const bf16x8*)(bhp + k2 + 8);
        pb[2] = *(const bf16x8*)(bmp + k2);     pb[3] = *(const bf16x8*)(bmp + k2 + 8);
        pah[0] = *(const bf16x8*)(xh0 + k2);    pah[1] = *(const bf16x8*)(xh1 + k2);
        pam[0] = *(const bf16x8*)(xm0 + k2);    pam[1] = *(const bf16x8*)(xm1 + k2);
      }
      bf16x8 fbh[4], fbm[4];
      #pragma unroll
      for (int j = 0; j < 4; j++) {
        fbh[j] = *(const bf16x8*)&Bh[wn + j * 16 + l15][qd * 8];
        fbm[j] = *(const bf16x8*)&Bm[wn + j * 16 + l15][qd * 8];
      }
      #pragma unroll
      for (int i = 0; i < 2; i++)
        #pragma unroll
        for (int j = 0; j < 4; j++) {
          floatx4 a = acc[i][j];
          a = __builtin_amdgcn_mfma_f32_16x16x32_bf16(fam[i], fbh[j], a, 0, 0, 0);
          a = __builtin_amdgcn_mfma_f32_16x16x32_bf16(fah[i], fbm[j], a, 0, 0, 0);
          a = __builtin_amdgcn_mfma_f32_16x16x32_bf16(fah[i], fbh[j], a, 0, 0, 0);
          acc[i][j] = a;
        }
    }
    #pragma unroll
    for (int i = 0; i < 2; i++)
      #pragma unroll
      for (int j = 0; j < 4; j++) {
        int col = wn + j * 16 + l15;
        float bb = bia[ns + col];
        #pragma unroll
        for (int r = 0; r < 4; r++) {
          int row = ms + wm + i * 16 + qd * 4 + r;
          float v = acc[i][j][r] + bb;
          size_t idx = ((size_t)head * SEQ + row) * 128 + col;
          outf[idx] = v;
          outb[idx] = (bf16)v;
        }
      }
  } else {
    // ---- V path: full 2048 rows, colsum fused; A direct from global ----
    int lin2 = lin - 1024;
    int ns = (lin2 & 15) * 128;
    int ms = (lin2 >> 4) * 64;
    bf16 (*Bs)[40] = (bf16(*)[40])(smem);
    float* colsum = (float*)(smem + 10240);
    if (t < 128) colsum[t] = 0.f;
    int fr0 = ms + wm + l15;
    int fr1 = ms + wm + 16 + l15;
    const bf16* a0 = Xh + (size_t)fr0 * DM + qd * 8;
    const bf16* a1 = Xh + (size_t)fr1 * DM + qd * 8;
    const bf16* bp = Wvh + (size_t)(ns + bnr) * DM + bkb;
    floatx4 acc[2][4];
    for (int i = 0; i < 2; i++)
      for (int j = 0; j < 4; j++) acc[i][j] = (floatx4){0.f, 0.f, 0.f, 0.f};

    bf16x8 pb[2], pa[2];
    pb[0] = *(const bf16x8*)(bp);  pb[1] = *(const bf16x8*)(bp + 8);
    pa[0] = *(const bf16x8*)(a0);  pa[1] = *(const bf16x8*)(a1);

    for (int kt = 0; kt < DM; kt += 32) {
      __syncthreads();
      *(bf16x8*)&Bs[bnr][bkb]     = pb[0];
      *(bf16x8*)&Bs[bnr][bkb + 8] = pb[1];
      __syncthreads();
      bf16x8 af[2];
      af[0] = pa[0]; af[1] = pa[1];
      if (kt + 32 < DM) {
        int k2 = kt + 32;
        pb[0] = *(const bf16x8*)(bp + k2);  pb[1] = *(const bf16x8*)(bp + k2 + 8);
        pa[0] = *(const bf16x8*)(a0 + k2);  pa[1] = *(const bf16x8*)(a1 + k2);
      }
      bf16x8 bfr[4];
      #pragma unroll
      for (int j = 0; j < 4; j++) bfr[j] = *(const bf16x8*)&Bs[wn + j * 16 + l15][qd * 8];
      #pragma unroll
      for (int i = 0; i < 2; i++)
        #pragma unroll
        for (int j = 0; j < 4; j++)
          acc[i][j] = __builtin_amdgcn_mfma_f32_16x16x32_bf16(af[i], bfr[j], acc[i][j], 0, 0, 0);
    }
    float part[4] = {0.f, 0.f, 0.f, 0.f};
    for (int i = 0; i < 2; i++) {
      for (int j = 0; j < 4; j++) {
        int n = ns + wn + j * 16 + l15;
        float bb = bv[n];
        for (int r = 0; r < 4; r++) {
          int m = ms + wm + i * 16 + qd * 4 + r;
          float v = acc[i][j][r] + bb;
          vf[(size_t)m * NP + n] = v;
          part[j] += v;
        }
      }
    }
    for (int j = 0; j < 4; j++)
      atomicAdd(&colsum[wn + j * 16 + l15], part[j]);
    __syncthreads();
    if (t < 128) atomicAdd(&sums[ns + t], colsum[t]);
  }
}

// ------- S1: scores via DIRECT global->register fragments ------------------
__global__ __launch_bounds__(256) void scores_min(
    const bf16* __restrict__ Qb, const bf16* __restrict__ Kb,
    const int* __restrict__ mc,
    unsigned* __restrict__ gmin) {
  int mcv = *mc;
  int h = blockIdx.x, s0 = blockIdx.y * 64;
  if (s0 >= mcv) return;
  int ntiles = (mcv + 63) >> 6;
  int half = (ntiles + 1) >> 1;
  int tbeg = blockIdx.z * half;
  int tend = ntiles < tbeg + half ? ntiles : tbeg + half;
  if (tbeg >= tend) return;
  __shared__ float lmin[64][4];
  int t = threadIdx.x, w = t >> 6, lane = t & 63, l15 = lane & 15, qd = lane >> 4;
  const bf16* Qh = Qb + (size_t)h * SEQ * 128;
  const bf16* Kh = Kb + (size_t)h * SEQ * 128;
  bf16x8 af[4][4];
  #pragma unroll
  for (int ksp = 0; ksp < 4; ksp++)
    #pragma unroll
    for (int i = 0; i < 4; i++)
      af[ksp][i] = *(const bf16x8*)(Qh + (size_t)(s0 + i * 16 + l15) * 128 + ksp * 32 + qd * 8);
  const bf16* kb = Kh + (size_t)(w * 16 + l15) * 128 + qd * 8;
  float rmin[4][4];
  for (int i = 0; i < 4; i++)
    for (int r = 0; r < 4; r++) rmin[i][r] = INFINITY;
  bf16x8 pre[4];
  #pragma unroll
  for (int ksp = 0; ksp < 4; ksp++)
    pre[ksp] = *(const bf16x8*)(kb + (size_t)tbeg * 8192 + ksp * 32);

  for (int tt = tbeg; tt < tend; tt++) {
    bf16x8 cur[4];
    #pragma unroll
    for (int ksp = 0; ksp < 4; ksp++) cur[ksp] = pre[ksp];
    if (tt + 1 < tend) {
      #pragma unroll
      for (int ksp = 0; ksp < 4; ksp++)
        pre[ksp] = *(const bf16x8*)(kb + (size_t)(tt + 1) * 8192 + ksp * 32);
    }
    floatx4 acc[4];
    for (int i = 0; i < 4; i++) acc[i] = (floatx4){0.f, 0.f, 0.f, 0.f};
    #pragma unroll
    for (int ksp = 0; ksp < 4; ksp++)
      #pragma unroll
      for (int i = 0; i < 4; i++)
        acc[i] = __builtin_amdgcn_mfma_f32_16x16x32_bf16(af[ksp][i], cur[ksp], acc[i], 0, 0, 0);
    bool okc = (tt * 64 + w * 16 + l15) < mcv;
    for (int i = 0; i < 4; i++)
      for (int r = 0; r < 4; r++)
        rmin[i][r] = fminf(rmin[i][r], okc ? acc[i][r] : INFINITY);
  }
  for (int m = 1; m < 16; m <<= 1)
    for (int i = 0; i < 4; i++)
      for (int r = 0; r < 4; r++)
        rmin[i][r] = fminf(rmin[i][r], __shfl_xor(rmin[i][r], m));
  if (l15 == 0)
    for (int i = 0; i < 4; i++)
      for (int r = 0; r < 4; r++)
        lmin[i * 16 + qd * 4 + r][w] = rmin[i][r];
  __syncthreads();
  if (t < 64) {
    int row = s0 + t;
    if (row < mcv) {
      float cm = fminf(fminf(lmin[t][0], lmin[t][1]), fminf(lmin[t][2], lmin[t][3]));
      atomicMin(&gmin[h * 2048 + row], enc_f(cm));
    }
  }
}

// ------- S2+rescore: collect candidates vs gmin+MARGIN, then rescore the
// block-local candidate list IN-PLACE (fp64 wave-reduce + atomicMin keys).
__global__ __launch_bounds__(256) void scores_collect(
    const bf16* __restrict__ Qb, const bf16* __restrict__ Kb,
    const float* __restrict__ qf, const float* __restrict__ kf,
    const int* __restrict__ midx, const int* __restrict__ mc,
    const unsigned* __restrict__ gmin,
    unsigned long long* __restrict__ keys) {
  int mcv = *mc;
  int h = blockIdx.x, s0 = blockIdx.y * 64;
  if (s0 >= mcv) return;
  int ntiles = (mcv + 63) >> 6;
  int half = (ntiles + 1) >> 1;
  int tbeg = blockIdx.z * half;
  int tend = ntiles < tbeg + half ? ntiles : tbeg + half;
  if (tbeg >= tend) return;
  __shared__ unsigned lbuf[LBUF];
  __shared__ int lcount;
  int t = threadIdx.x, w = t >> 6, lane = t & 63, l15 = lane & 15, qd = lane >> 4;
  if (t == 0) lcount = 0;
  const bf16* Qh = Qb + (size_t)h * SEQ * 128;
  const bf16* Kh = Kb + (size_t)h * SEQ * 128;
  bf16x8 af[4][4];
  #pragma unroll
  for (int ksp = 0; ksp < 4; ksp++)
    #pragma unroll
    for (int i = 0; i < 4; i++)
      af[ksp][i] = *(const bf16x8*)(Qh + (size_t)(s0 + i * 16 + l15) * 128 + ksp * 32 + qd * 8);
  float fm[4][4];
  for (int i = 0; i < 4; i++)
    for (int r = 0; r < 4; r++) {
      int row = s0 + i * 16 + qd * 4 + r;
      fm[i][r] = (row < mcv) ? dec_f(gmin[h * 2048 + row]) + MARGIN : -INFINITY;
    }
  const bf16* kb = Kh + (size_t)(w * 16 + l15) * 128 + qd * 8;
  bf16x8 pre[4];
  #pragma unroll
  for (int ksp = 0; ksp < 4; ksp++)
    pre[ksp] = *(const bf16x8*)(kb + (size_t)tbeg * 8192 + ksp * 32);
  __syncthreads();                  // lcount visible

  for (int tt = tbeg; tt < tend; tt++) {
    bf16x8 cur[4];
    #pragma unroll
    for (int ksp = 0; ksp < 4; ksp++) cur[ksp] = pre[ksp];
    if (tt + 1 < tend) {
      #pragma unroll
      for (int ksp = 0; ksp < 4; ksp++)
        pre[ksp] = *(const bf16x8*)(kb + (size_t)(tt + 1) * 8192 + ksp * 32);
    }
    floatx4 acc[4];
    for (int i = 0; i < 4; i++) acc[i] = (floatx4){0.f, 0.f, 0.f, 0.f};
    #pragma unroll
    for (int ksp = 0; ksp < 4; ksp++)
      #pragma unroll
      for (int i = 0; i < 4; i++)
        acc[i] = __builtin_amdgcn_mfma_f32_16x16x32_bf16(af[ksp][i], cur[ksp], acc[i], 0, 0, 0);
    int tg = tt * 64 + w * 16 + l15;
    if (tg < mcv) {
      for (int i = 0; i < 4; i++)
        for (int r = 0; r < 4; r++) {
          if (acc[i][r] <= fm[i][r]) {
            int rr = s0 + i * 16 + qd * 4 + r;
            int lp = atomicAdd(&lcount, 1);
            if (lp < LBUF) {
              lbuf[lp] = ((unsigned)rr << 11) | (unsigned)tg;
            } else {
              // pathological overflow: rescore this candidate serially in-lane
              const float* qrow = qf + ((size_t)h * SEQ + rr) * 128;
              const float* krow = kf + ((size_t)h * SEQ + tg) * 128;
              double d = 0.0;
              for (int k = 0; k < 128; k++)
                d += (double)qrow[k] * (double)krow[k];
              long long bll = __double_as_longlong(d);
              unsigned long long ub = (bll >= 0)
                  ? ((unsigned long long)bll | 0x8000000000000000ULL)
                  : ~(unsigned long long)bll;
              unsigned long long key = (ub & ~2047ULL) | (unsigned long long)midx[tg];
              atomicMin(&keys[(size_t)h * SEQ + midx[rr]], key);
            }
          }
        }
    }
  }
  __syncthreads();
  int cnt = lcount; if (cnt > LBUF) cnt = LBUF;
  // in-place fp64 rescore of the block-local candidate list (wave-parallel)
  for (int c = w; c < cnt; c += 4) {
    unsigned u = lbuf[c];
    int cs = (u >> 11) & 2047, ct = u & 2047;
    floatx2 qv = *(const floatx2*)(qf + ((size_t)h * SEQ + cs) * 128 + lane * 2);
    floatx2 kv = *(const floatx2*)(kf + ((size_t)h * SEQ + ct) * 128 + lane * 2);
    double d = (double)qv[0] * (double)kv[0] + (double)qv[1] * (double)kv[1];
    for (int off = 32; off; off >>= 1) d += __shfl_down(d, off);
    if (lane == 0) {
      int sorig = midx[cs], torig = midx[ct];
      long long bll = __double_as_longlong(d);
      unsigned long long ub = (bll >= 0)
          ? ((unsigned long long)bll | 0x8000000000000000ULL)
          : ~(unsigned long long)bll;
      unsigned long long key = (ub & ~2047ULL) | (unsigned long long)torig;
      atomicMin(&keys[(size_t)h * SEQ + sorig], key);
    }
  }
}

// ---------------- gather / mean, fp32 out, x4 vectorized --------------------
__global__ __launch_bounds__(256) void assemble(
    const float* __restrict__ V, const float* __restrict__ sums,
    const int* __restrict__ mask, const unsigned long long* __restrict__ keys,
    float* __restrict__ out) {
  int q = blockIdx.x * 256 + threadIdx.x;     // covers 2048*2048/4
  int idx = q * 4;
  int s = idx >> 11, n = idx & 2047, h = n >> 7;
  floatx4 val;
  if (mask[s]) {
    int tt = (int)(keys[(size_t)h * SEQ + s] & 2047ULL);
    val = *(const floatx4*)(V + (size_t)tt * NP + n);
  } else {
    floatx4 sv = *(const floatx4*)(sums + n);
    for (int j = 0; j < 4; j++) val[j] = sv[j] * (1.0f / 2048.0f);
  }
  *(floatx4*)(out + idx) = val;
}

extern "C" void kernel_launch(void* const* d_in, const int* in_sizes, int n_in,
                              void* d_out, int out_size, void* d_ws, size_t ws_size,
                              hipStream_t stream) {
  (void)in_sizes; (void)n_in; (void)out_size; (void)ws_size;
  const float* X    = (const float*)d_in[0];
  const void*  mraw = d_in[1];
  const float* Wq   = (const float*)d_in[2];
  const float* bq   = (const float*)d_in[3];
  const float* Wk   = (const float*)d_in[4];
  const float* bk   = (const float*)d_in[5];
  const float* Wv   = (const float*)d_in[6];
  const float* bv   = (const float*)d_in[7];

  char* ws = (char*)d_ws;
  float* qf  = (float*)ws;                                  // 0..16MB
  float* kf  = (float*)(ws + ((size_t)16 << 20));           // 16..32MB
  bf16*  qbf = (bf16*) (ws + ((size_t)32 << 20));           // 32..40MB
  bf16*  kbf = (bf16*) (ws + ((size_t)40 << 20));           // 40..48MB
  bf16* wqh = (bf16*)(ws + ((size_t)48 << 20));
  bf16* wqm = (bf16*)(ws + ((size_t)52 << 20));
  bf16* wkh = (bf16*)(ws + ((size_t)56 << 20));
  bf16* wkm = (bf16*)(ws + ((size_t)60 << 20));
  char* misc = ws + ((size_t)72 << 20);
  int*   maskw  = (int*)misc;                                   // 8KB
  int*   midx   = (int*)(misc + (8 << 10));                     // 8KB
  int*   mc     = (int*)(misc + (16 << 10));                    // 4B
  float* sums   = (float*)(misc + (32 << 10));                  // 8KB
  unsigned long long* keys = (unsigned long long*)(misc + (64 << 10));  // 256KB
  unsigned* gmin = (unsigned*)(misc + (320 << 10));             // 128KB
  // 73..89MB: X splits + Wv high split; 89..105MB: vf (own region — proj qk
  // and v blocks run concurrently, so vf must not overlay the W splits)
  bf16* xh  = (bf16*)(ws + ((size_t)73 << 20));             // 4MB
  bf16* xm  = (bf16*)(ws + ((size_t)77 << 20));             // 4MB
  bf16* tvh = (bf16*)(ws + ((size_t)85 << 20));             // 4MB
  float* vf = (float*)(ws + ((size_t)89 << 20));            // 16MB
  float* out = (float*)d_out;

  prep<<<8225, 256, 0, stream>>>(mraw, X, Wq, Wk, Wv,
                                 maskw, midx, mc, sums, keys, gmin,
                                 xh, xm, wqh, wqm, wkh, wkm, tvh);
  proj_fused<<<1536, 256, 0, stream>>>(xh, xm, wqh, wqm, wkh, wkm, tvh,
                                       bq, bk, bv, midx, mc,
                                       qf, kf, qbf, kbf, vf, sums);
  scores_min<<<dim3(16, 32, 2), 256, 0, stream>>>(qbf, kbf, mc, gmin);
  scores_collect<<<dim3(16, 32, 2), 256, 0, stream>>>(qbf, kbf, qf, kf, midx, mc, gmin, keys);
  assemble<<<4096, 256, 0, stream>>>(vf, sums, maskw, keys, out);
}

// Round 16
// 201.544 us; speedup vs baseline: 1.0897x; 1.0897x over previous
//
#include <hip/hip_runtime.h>
#include <hip/hip_bf16.h>
#include <cfloat>
#include <math.h>

typedef __bf16 bf16;
typedef __bf16 bf16x4 __attribute__((ext_vector_type(4)));
typedef __bf16 bf16x8 __attribute__((ext_vector_type(8)));
typedef float  floatx4 __attribute__((ext_vector_type(4)));
typedef float  floatx2 __attribute__((ext_vector_type(2)));

#define SEQ 2048
#define DM  1024
#define NP  2048
#define MARGIN 0.5f
#define LBUF 1024

__device__ __forceinline__ unsigned enc_f(float f) {
  unsigned b = __float_as_uint(f);
  return ((int)b >= 0) ? (b | 0x80000000u) : ~b;
}
__device__ __forceinline__ float dec_f(unsigned u) {
  return (u & 0x80000000u) ? __uint_as_float(u & 0x7fffffffu) : __uint_as_float(~u);
}

// ===== fused prep: mask detect/compaction + inits + X split + W splits ======
// blocks [0,33): mask_prep; [33,2081): split_x; [2081,8225): split_w.
__global__ __launch_bounds__(256) void prep(
    const void* __restrict__ mraw, const float* __restrict__ X,
    const float* __restrict__ Wq, const float* __restrict__ Wk,
    const float* __restrict__ Wv,
    int* __restrict__ maskw, int* __restrict__ midx, int* __restrict__ mc,
    float* __restrict__ sums,
    unsigned long long* __restrict__ keys, unsigned* __restrict__ gmin,
    bf16* __restrict__ Xh, bf16* __restrict__ Xm,
    bf16* __restrict__ Tqh, bf16* __restrict__ Tqm,
    bf16* __restrict__ Tkh, bf16* __restrict__ Tkm,
    bf16* __restrict__ Tvh) {
  int b = blockIdx.x, t = threadIdx.x;
  if (b < 33) {
    if (b > 0) {
      int bb = b - 1;                 // 0..31
      for (int j = 0; j < 4; j++) {
        int i = bb * 1024 + j * 256 + t;
        keys[i] = ~0ULL;
        gmin[i] = 0xFFFFFFFFu;
      }
      if (bb == 0) for (int i = t; i < 2048; i += 256) sums[i] = 0.f;
      return;
    }
    __shared__ int flags;
    __shared__ int lmask[2048];
    if (t == 0) flags = 0;
    __syncthreads();
    const unsigned short* u16 = (const unsigned short*)mraw;
    const unsigned* u32 = (const unsigned*)mraw;
    int f = 0;
    for (int i = t; i < 1024; i += 256) {
      unsigned short v = u16[i];
      if (v != 0 && v != 0x3F80u) f |= 1;
      if ((i & 1) == 0 && v == 0x3F80u) f |= 2;
    }
    for (int i = t; i < 512; i += 256)
      if (u32[i] > 1u) f |= 4;
    if (f) atomicOr(&flags, f);
    __syncthreads();
    int fl = flags;
    int mode;
    if (!(fl & 1)) mode = (fl & 2) ? 2 : 3;
    else           mode = (fl & 4) ? 1 : 0;
    for (int s = t; s < SEQ; s += 256) {
      int m;
      if (mode == 0)      m = (((const int*)mraw)[s] != 0);
      else if (mode == 1) m = (((const unsigned char*)mraw)[s] != 0);
      else if (mode == 2) m = (u16[s] != 0);
      else                m = (((const float*)mraw)[s] != 0.0f);
      maskw[s] = m; lmask[s] = m;
    }
    __syncthreads();
    if (t < 64) {
      int base = 0;
      for (int c = 0; c < 32; c++) {
        int s = c * 64 + t;
        bool m = lmask[s] != 0;
        unsigned long long bal = __ballot(m);
        if (m) midx[base + __popcll(bal & ((1ULL << t) - 1ULL))] = s;
        base += __popcll(bal);
      }
      if (t == 0) *mc = base;
    }
    return;
  }
  if (b < 2081) {
    // ---- split_x: X -> 2-way bf16, row-major ----
    int i = (b - 33) * 256 + t;
    floatx4 v = *(const floatx4*)(X + (size_t)i * 4);
    bf16x4 hv, mv;
    #pragma unroll
    for (int j = 0; j < 4; j++) {
      float x = v[j];
      bf16 h = (bf16)x; float r1 = x - (float)h;
      hv[j] = h; mv[j] = (bf16)r1;
    }
    *(bf16x4*)(Xh + (size_t)i * 4) = hv;
    *(bf16x4*)(Xm + (size_t)i * 4) = mv;
    return;
  }
  // ---- split_w: transposed bf16 splits; z=0 Wq(2), z=1 Wk(2), z=2 Wv(h) ----
  int bb = b - 2081;
  int z = bb >> 11, rem = bb & 2047;
  int n0 = (rem & 63) * 32, k0 = (rem >> 6) * 32;
  const float* W = (z == 0) ? Wq : (z == 1) ? Wk : Wv;
  bf16* Th = (z == 0) ? Tqh : (z == 1) ? Tkh : Tvh;
  bf16* Tm = (z == 0) ? Tqm : Tkm;
  __shared__ float tile[32][33];
  int r = t >> 3, c4 = (t & 7) * 4;
  floatx4 v = *(const floatx4*)(W + (size_t)(k0 + r) * NP + n0 + c4);
  tile[r][c4 + 0] = v[0]; tile[r][c4 + 1] = v[1];
  tile[r][c4 + 2] = v[2]; tile[r][c4 + 3] = v[3];
  __syncthreads();
  bf16x4 hv, mv;
  #pragma unroll
  for (int j = 0; j < 4; j++) {
    float x = tile[c4 + j][r];
    bf16 h = (bf16)x; float r1 = x - (float)h;
    hv[j] = h; mv[j] = (bf16)r1;
  }
  size_t base = (size_t)(n0 + r) * DM + k0 + c4;
  *(bf16x4*)(Th + base) = hv;
  if (z < 2)
    *(bf16x4*)(Tm + base) = mv;
}

// ===== fused projections: blocks [0,1024) = Q/K, [1024,1536) = V + colsum ===
// LDS row stride [40] = 80B, a multiple of 16B — REQUIRED for ds_*_b128
// (the [34]=68B stride broke alignment and scalarized all LDS ops). A-tiles
// stay LDS-staged: staging converts scattered per-lane fragment gathers into
// coalesced wave-wide loads (the A-direct variant regressed 67->84us).
__global__ __launch_bounds__(256) void proj_fused(
    const bf16* __restrict__ Xh, const bf16* __restrict__ Xm,
    const bf16* __restrict__ Qh_, const bf16* __restrict__ Qm_,
    const bf16* __restrict__ Kh_, const bf16* __restrict__ Km_,
    const bf16* __restrict__ Wvh,
    const float* __restrict__ bq, const float* __restrict__ bk,
    const float* __restrict__ bv,
    const int* __restrict__ midx, const int* __restrict__ mc,
    float* __restrict__ qf, float* __restrict__ kf,
    bf16* __restrict__ qbf, bf16* __restrict__ kbf,
    float* __restrict__ vf, float* __restrict__ sums) {
  __shared__ alignas(16) char smem[30720];
  int lin = blockIdx.x;
  int t = threadIdx.x, w = t >> 6, lane = t & 63, l15 = lane & 15, qd = lane >> 4;
  int wm = (w & 1) * 32, wn = (w >> 1) * 64;
  int amr = t >> 2, akb = (t & 3) * 8;
  int bnr = t >> 1, bkb = (t & 1) * 16;
  if (lin < 1024) {
    int mcv = *mc;
    int z    = lin & 1;
    int head = (lin >> 1) & 15;
    int ms   = (lin >> 5) * 64;
    if (mcv == 0 || ms >= mcv) return;
    const bf16* WTh = z ? Kh_ : Qh_;
    const bf16* WTm = z ? Km_ : Qm_;
    const float* bia = z ? bk : bq;
    float* outf = z ? kf : qf;
    bf16*  outb = z ? kbf : qbf;
    int ns = head * 128;
    bf16 (*Ah)[40] = (bf16(*)[40])(smem);
    bf16 (*Am)[40] = (bf16(*)[40])(smem + 5120);
    bf16 (*Bh)[40] = (bf16(*)[40])(smem + 10240);
    bf16 (*Bm)[40] = (bf16(*)[40])(smem + 20480);
    int cr = ms + amr;
    size_t arow = (size_t)midx[cr < mcv ? cr : (mcv - 1)] * DM + akb;
    const bf16* xhp = Xh + arow;
    const bf16* xmp = Xm + arow;
    const bf16* bhp = WTh + (size_t)(ns + bnr) * DM + bkb;
    const bf16* bmp = WTm + (size_t)(ns + bnr) * DM + bkb;

    floatx4 acc[2][4];
    for (int i = 0; i < 2; i++)
      for (int j = 0; j < 4; j++) acc[i][j] = (floatx4){0.f, 0.f, 0.f, 0.f};

    bf16x8 pa[2], pb[4];
    pa[0] = *(const bf16x8*)(xhp);
    pa[1] = *(const bf16x8*)(xmp);
    pb[0] = *(const bf16x8*)(bhp);     pb[1] = *(const bf16x8*)(bhp + 8);
    pb[2] = *(const bf16x8*)(bmp);     pb[3] = *(const bf16x8*)(bmp + 8);

    for (int kt = 0; kt < DM; kt += 32) {
      __syncthreads();
      *(bf16x8*)&Ah[amr][akb] = pa[0];
      *(bf16x8*)&Am[amr][akb] = pa[1];
      *(bf16x8*)&Bh[bnr][bkb]     = pb[0];
      *(bf16x8*)&Bh[bnr][bkb + 8] = pb[1];
      *(bf16x8*)&Bm[bnr][bkb]     = pb[2];
      *(bf16x8*)&Bm[bnr][bkb + 8] = pb[3];
      __syncthreads();
      if (kt + 32 < DM) {
        int k2 = kt + 32;
        pa[0] = *(const bf16x8*)(xhp + k2);
        pa[1] = *(const bf16x8*)(xmp + k2);
        pb[0] = *(const bf16x8*)(bhp + k2);     pb[1] = *(const bf16x8*)(bhp + k2 + 8);
        pb[2] = *(const bf16x8*)(bmp + k2);     pb[3] = *(const bf16x8*)(bmp + k2 + 8);
      }
      bf16x8 fah[2], fam[2], fbh[4], fbm[4];
      #pragma unroll
      for (int i = 0; i < 2; i++) {
        fah[i] = *(const bf16x8*)&Ah[wm + i * 16 + l15][qd * 8];
        fam[i] = *(const bf16x8*)&Am[wm + i * 16 + l15][qd * 8];
      }
      #pragma unroll
      for (int j = 0; j < 4; j++) {
        fbh[j] = *(const bf16x8*)&Bh[wn + j * 16 + l15][qd * 8];
        fbm[j] = *(const bf16x8*)&Bm[wn + j * 16 + l15][qd * 8];
      }
      #pragma unroll
      for (int i = 0; i < 2; i++)
        #pragma unroll
        for (int j = 0; j < 4; j++) {
          floatx4 a = acc[i][j];
          a = __builtin_amdgcn_mfma_f32_16x16x32_bf16(fam[i], fbh[j], a, 0, 0, 0);
          a = __builtin_amdgcn_mfma_f32_16x16x32_bf16(fah[i], fbm[j], a, 0, 0, 0);
          a = __builtin_amdgcn_mfma_f32_16x16x32_bf16(fah[i], fbh[j], a, 0, 0, 0);
          acc[i][j] = a;
        }
    }
    #pragma unroll
    for (int i = 0; i < 2; i++)
      #pragma unroll
      for (int j = 0; j < 4; j++) {
        int col = wn + j * 16 + l15;
        float bb = bia[ns + col];
        #pragma unroll
        for (int r = 0; r < 4; r++) {
          int row = ms + wm + i * 16 + qd * 4 + r;
          float v = acc[i][j][r] + bb;
          size_t idx = ((size_t)head * SEQ + row) * 128 + col;
          outf[idx] = v;
          outb[idx] = (bf16)v;
        }
      }
  } else {
    // ---- V path: full 2048 rows, colsum fused ----
    int lin2 = lin - 1024;
    int ns = (lin2 & 15) * 128;
    int ms = (lin2 >> 4) * 64;
    bf16 (*As)[40] = (bf16(*)[40])(smem);
    bf16 (*Bs)[40] = (bf16(*)[40])(smem + 5120);
    float* colsum = (float*)(smem + 15360);
    if (t < 128) colsum[t] = 0.f;
    const bf16* ap = Xh  + (size_t)(ms + amr) * DM + akb;
    const bf16* bp = Wvh + (size_t)(ns + bnr) * DM + bkb;
    floatx4 acc[2][4];
    for (int i = 0; i < 2; i++)
      for (int j = 0; j < 4; j++) acc[i][j] = (floatx4){0.f, 0.f, 0.f, 0.f};

    bf16x8 pa, pb[2];
    pa    = *(const bf16x8*)(ap);
    pb[0] = *(const bf16x8*)(bp);  pb[1] = *(const bf16x8*)(bp + 8);

    for (int kt = 0; kt < DM; kt += 32) {
      __syncthreads();
      *(bf16x8*)&As[amr][akb]     = pa;
      *(bf16x8*)&Bs[bnr][bkb]     = pb[0];
      *(bf16x8*)&Bs[bnr][bkb + 8] = pb[1];
      __syncthreads();
      if (kt + 32 < DM) {
        int k2 = kt + 32;
        pa    = *(const bf16x8*)(ap + k2);
        pb[0] = *(const bf16x8*)(bp + k2);  pb[1] = *(const bf16x8*)(bp + k2 + 8);
      }
      bf16x8 af[2], bfr[4];
      #pragma unroll
      for (int i = 0; i < 2; i++) af[i]  = *(const bf16x8*)&As[wm + i * 16 + l15][qd * 8];
      #pragma unroll
      for (int j = 0; j < 4; j++) bfr[j] = *(const bf16x8*)&Bs[wn + j * 16 + l15][qd * 8];
      #pragma unroll
      for (int i = 0; i < 2; i++)
        #pragma unroll
        for (int j = 0; j < 4; j++)
          acc[i][j] = __builtin_amdgcn_mfma_f32_16x16x32_bf16(af[i], bfr[j], acc[i][j], 0, 0, 0);
    }
    float part[4] = {0.f, 0.f, 0.f, 0.f};
    for (int i = 0; i < 2; i++) {
      for (int j = 0; j < 4; j++) {
        int n = ns + wn + j * 16 + l15;
        float bb = bv[n];
        for (int r = 0; r < 4; r++) {
          int m = ms + wm + i * 16 + qd * 4 + r;
          float v = acc[i][j][r] + bb;
          vf[(size_t)m * NP + n] = v;
          part[j] += v;
        }
      }
    }
    for (int j = 0; j < 4; j++)
      atomicAdd(&colsum[wn + j * 16 + l15], part[j]);
    __syncthreads();
    if (t < 128) atomicAdd(&sums[ns + t], colsum[t]);
  }
}

// ------- S1: scores via DIRECT global->register fragments ------------------
__global__ __launch_bounds__(256) void scores_min(
    const bf16* __restrict__ Qb, const bf16* __restrict__ Kb,
    const int* __restrict__ mc,
    unsigned* __restrict__ gmin) {
  int mcv = *mc;
  int h = blockIdx.x, s0 = blockIdx.y * 64;
  if (s0 >= mcv) return;
  int ntiles = (mcv + 63) >> 6;
  int half = (ntiles + 1) >> 1;
  int tbeg = blockIdx.z * half;
  int tend = ntiles < tbeg + half ? ntiles : tbeg + half;
  if (tbeg >= tend) return;
  __shared__ float lmin[64][4];
  int t = threadIdx.x, w = t >> 6, lane = t & 63, l15 = lane & 15, qd = lane >> 4;
  const bf16* Qh = Qb + (size_t)h * SEQ * 128;
  const bf16* Kh = Kb + (size_t)h * SEQ * 128;
  bf16x8 af[4][4];
  #pragma unroll
  for (int ksp = 0; ksp < 4; ksp++)
    #pragma unroll
    for (int i = 0; i < 4; i++)
      af[ksp][i] = *(const bf16x8*)(Qh + (size_t)(s0 + i * 16 + l15) * 128 + ksp * 32 + qd * 8);
  const bf16* kb = Kh + (size_t)(w * 16 + l15) * 128 + qd * 8;
  float rmin[4][4];
  for (int i = 0; i < 4; i++)
    for (int r = 0; r < 4; r++) rmin[i][r] = INFINITY;
  bf16x8 pre[4];
  #pragma unroll
  for (int ksp = 0; ksp < 4; ksp++)
    pre[ksp] = *(const bf16x8*)(kb + (size_t)tbeg * 8192 + ksp * 32);

  for (int tt = tbeg; tt < tend; tt++) {
    bf16x8 cur[4];
    #pragma unroll
    for (int ksp = 0; ksp < 4; ksp++) cur[ksp] = pre[ksp];
    if (tt + 1 < tend) {
      #pragma unroll
      for (int ksp = 0; ksp < 4; ksp++)
        pre[ksp] = *(const bf16x8*)(kb + (size_t)(tt + 1) * 8192 + ksp * 32);
    }
    floatx4 acc[4];
    for (int i = 0; i < 4; i++) acc[i] = (floatx4){0.f, 0.f, 0.f, 0.f};
    #pragma unroll
    for (int ksp = 0; ksp < 4; ksp++)
      #pragma unroll
      for (int i = 0; i < 4; i++)
        acc[i] = __builtin_amdgcn_mfma_f32_16x16x32_bf16(af[ksp][i], cur[ksp], acc[i], 0, 0, 0);
    bool okc = (tt * 64 + w * 16 + l15) < mcv;
    for (int i = 0; i < 4; i++)
      for (int r = 0; r < 4; r++)
        rmin[i][r] = fminf(rmin[i][r], okc ? acc[i][r] : INFINITY);
  }
  for (int m = 1; m < 16; m <<= 1)
    for (int i = 0; i < 4; i++)
      for (int r = 0; r < 4; r++)
        rmin[i][r] = fminf(rmin[i][r], __shfl_xor(rmin[i][r], m));
  if (l15 == 0)
    for (int i = 0; i < 4; i++)
      for (int r = 0; r < 4; r++)
        lmin[i * 16 + qd * 4 + r][w] = rmin[i][r];
  __syncthreads();
  if (t < 64) {
    int row = s0 + t;
    if (row < mcv) {
      float cm = fminf(fminf(lmin[t][0], lmin[t][1]), fminf(lmin[t][2], lmin[t][3]));
      atomicMin(&gmin[h * 2048 + row], enc_f(cm));
    }
  }
}

// ------- S2+rescore: collect candidates vs gmin+MARGIN, then rescore the
// block-local candidate list IN-PLACE (fp64 wave-reduce + atomicMin keys).
__global__ __launch_bounds__(256) void scores_collect(
    const bf16* __restrict__ Qb, const bf16* __restrict__ Kb,
    const float* __restrict__ qf, const float* __restrict__ kf,
    const int* __restrict__ midx, const int* __restrict__ mc,
    const unsigned* __restrict__ gmin,
    unsigned long long* __restrict__ keys) {
  int mcv = *mc;
  int h = blockIdx.x, s0 = blockIdx.y * 64;
  if (s0 >= mcv) return;
  int ntiles = (mcv + 63) >> 6;
  int half = (ntiles + 1) >> 1;
  int tbeg = blockIdx.z * half;
  int tend = ntiles < tbeg + half ? ntiles : tbeg + half;
  if (tbeg >= tend) return;
  __shared__ unsigned lbuf[LBUF];
  __shared__ int lcount;
  int t = threadIdx.x, w = t >> 6, lane = t & 63, l15 = lane & 15, qd = lane >> 4;
  if (t == 0) lcount = 0;
  const bf16* Qh = Qb + (size_t)h * SEQ * 128;
  const bf16* Kh = Kb + (size_t)h * SEQ * 128;
  bf16x8 af[4][4];
  #pragma unroll
  for (int ksp = 0; ksp < 4; ksp++)
    #pragma unroll
    for (int i = 0; i < 4; i++)
      af[ksp][i] = *(const bf16x8*)(Qh + (size_t)(s0 + i * 16 + l15) * 128 + ksp * 32 + qd * 8);
  float fm[4][4];
  for (int i = 0; i < 4; i++)
    for (int r = 0; r < 4; r++) {
      int row = s0 + i * 16 + qd * 4 + r;
      fm[i][r] = (row < mcv) ? dec_f(gmin[h * 2048 + row]) + MARGIN : -INFINITY;
    }
  const bf16* kb = Kh + (size_t)(w * 16 + l15) * 128 + qd * 8;
  bf16x8 pre[4];
  #pragma unroll
  for (int ksp = 0; ksp < 4; ksp++)
    pre[ksp] = *(const bf16x8*)(kb + (size_t)tbeg * 8192 + ksp * 32);
  __syncthreads();                  // lcount visible

  for (int tt = tbeg; tt < tend; tt++) {
    bf16x8 cur[4];
    #pragma unroll
    for (int ksp = 0; ksp < 4; ksp++) cur[ksp] = pre[ksp];
    if (tt + 1 < tend) {
      #pragma unroll
      for (int ksp = 0; ksp < 4; ksp++)
        pre[ksp] = *(const bf16x8*)(kb + (size_t)(tt + 1) * 8192 + ksp * 32);
    }
    floatx4 acc[4];
    for (int i = 0; i < 4; i++) acc[i] = (floatx4){0.f, 0.f, 0.f, 0.f};
    #pragma unroll
    for (int ksp = 0; ksp < 4; ksp++)
      #pragma unroll
      for (int i = 0; i < 4; i++)
        acc[i] = __builtin_amdgcn_mfma_f32_16x16x32_bf16(af[ksp][i], cur[ksp], acc[i], 0, 0, 0);
    int tg = tt * 64 + w * 16 + l15;
    if (tg < mcv) {
      for (int i = 0; i < 4; i++)
        for (int r = 0; r < 4; r++) {
          if (acc[i][r] <= fm[i][r]) {
            int rr = s0 + i * 16 + qd * 4 + r;
            int lp = atomicAdd(&lcount, 1);
            if (lp < LBUF) {
              lbuf[lp] = ((unsigned)rr << 11) | (unsigned)tg;
            } else {
              // pathological overflow: rescore this candidate serially in-lane
              const float* qrow = qf + ((size_t)h * SEQ + rr) * 128;
              const float* krow = kf + ((size_t)h * SEQ + tg) * 128;
              double d = 0.0;
              for (int k = 0; k < 128; k++)
                d += (double)qrow[k] * (double)krow[k];
              long long bll = __double_as_longlong(d);
              unsigned long long ub = (bll >= 0)
                  ? ((unsigned long long)bll | 0x8000000000000000ULL)
                  : ~(unsigned long long)bll;
              unsigned long long key = (ub & ~2047ULL) | (unsigned long long)midx[tg];
              atomicMin(&keys[(size_t)h * SEQ + midx[rr]], key);
            }
          }
        }
    }
  }
  __syncthreads();
  int cnt = lcount; if (cnt > LBUF) cnt = LBUF;
  // in-place fp64 rescore of the block-local candidate list (wave-parallel)
  for (int c = w; c < cnt; c += 4) {
    unsigned u = lbuf[c];
    int cs = (u >> 11) & 2047, ct = u & 2047;
    floatx2 qv = *(const floatx2*)(qf + ((size_t)h * SEQ + cs) * 128 + lane * 2);
    floatx2 kv = *(const floatx2*)(kf + ((size_t)h * SEQ + ct) * 128 + lane * 2);
    double d = (double)qv[0] * (double)kv[0] + (double)qv[1] * (double)kv[1];
    for (int off = 32; off; off >>= 1) d += __shfl_down(d, off);
    if (lane == 0) {
      int sorig = midx[cs], torig = midx[ct];
      long long bll = __double_as_longlong(d);
      unsigned long long ub = (bll >= 0)
          ? ((unsigned long long)bll | 0x8000000000000000ULL)
          : ~(unsigned long long)bll;
      unsigned long long key = (ub & ~2047ULL) | (unsigned long long)torig;
      atomicMin(&keys[(size_t)h * SEQ + sorig], key);
    }
  }
}

// ---------------- gather / mean, fp32 out, x4 vectorized --------------------
__global__ __launch_bounds__(256) void assemble(
    const float* __restrict__ V, const float* __restrict__ sums,
    const int* __restrict__ mask, const unsigned long long* __restrict__ keys,
    float* __restrict__ out) {
  int q = blockIdx.x * 256 + threadIdx.x;     // covers 2048*2048/4
  int idx = q * 4;
  int s = idx >> 11, n = idx & 2047, h = n >> 7;
  floatx4 val;
  if (mask[s]) {
    int tt = (int)(keys[(size_t)h * SEQ + s] & 2047ULL);
    val = *(const floatx4*)(V + (size_t)tt * NP + n);
  } else {
    floatx4 sv = *(const floatx4*)(sums + n);
    for (int j = 0; j < 4; j++) val[j] = sv[j] * (1.0f / 2048.0f);
  }
  *(floatx4*)(out + idx) = val;
}

extern "C" void kernel_launch(void* const* d_in, const int* in_sizes, int n_in,
                              void* d_out, int out_size, void* d_ws, size_t ws_size,
                              hipStream_t stream) {
  (void)in_sizes; (void)n_in; (void)out_size; (void)ws_size;
  const float* X    = (const float*)d_in[0];
  const void*  mraw = d_in[1];
  const float* Wq   = (const float*)d_in[2];
  const float* bq   = (const float*)d_in[3];
  const float* Wk   = (const float*)d_in[4];
  const float* bk   = (const float*)d_in[5];
  const float* Wv   = (const float*)d_in[6];
  const float* bv   = (const float*)d_in[7];

  char* ws = (char*)d_ws;
  float* qf  = (float*)ws;                                  // 0..16MB
  float* kf  = (float*)(ws + ((size_t)16 << 20));           // 16..32MB
  bf16*  qbf = (bf16*) (ws + ((size_t)32 << 20));           // 32..40MB
  bf16*  kbf = (bf16*) (ws + ((size_t)40 << 20));           // 40..48MB
  bf16* wqh = (bf16*)(ws + ((size_t)48 << 20));
  bf16* wqm = (bf16*)(ws + ((size_t)52 << 20));
  bf16* wkh = (bf16*)(ws + ((size_t)56 << 20));
  bf16* wkm = (bf16*)(ws + ((size_t)60 << 20));
  char* misc = ws + ((size_t)72 << 20);
  int*   maskw  = (int*)misc;                                   // 8KB
  int*   midx   = (int*)(misc + (8 << 10));                     // 8KB
  int*   mc     = (int*)(misc + (16 << 10));                    // 4B
  float* sums   = (float*)(misc + (32 << 10));                  // 8KB
  unsigned long long* keys = (unsigned long long*)(misc + (64 << 10));  // 256KB
  unsigned* gmin = (unsigned*)(misc + (320 << 10));             // 128KB
  // 73..89MB: X splits + Wv high split; 89..105MB: vf (own region — proj qk
  // and v blocks run concurrently, so vf must not overlay the W splits)
  bf16* xh  = (bf16*)(ws + ((size_t)73 << 20));             // 4MB
  bf16* xm  = (bf16*)(ws + ((size_t)77 << 20));             // 4MB
  bf16* tvh = (bf16*)(ws + ((size_t)85 << 20));             // 4MB
  float* vf = (float*)(ws + ((size_t)89 << 20));            // 16MB
  float* out = (float*)d_out;

  prep<<<8225, 256, 0, stream>>>(mraw, X, Wq, Wk, Wv,
                                 maskw, midx, mc, sums, keys, gmin,
                                 xh, xm, wqh, wqm, wkh, wkm, tvh);
  proj_fused<<<1536, 256, 0, stream>>>(xh, xm, wqh, wqm, wkh, wkm, tvh,
                                       bq, bk, bv, midx, mc,
                                       qf, kf, qbf, kbf, vf, sums);
  scores_min<<<dim3(16, 32, 2), 256, 0, stream>>>(qbf, kbf, mc, gmin);
  scores_collect<<<dim3(16, 32, 2), 256, 0, stream>>>(qbf, kbf, qf, kf, midx, mc, gmin, keys);
  assemble<<<4096, 256, 0, stream>>>(vf, sums, maskw, keys, out);
}